// Round 1
// baseline (37.004 us; speedup 1.0000x reference)
//
#include <hip/hip_runtime.h>

// MLP_64450279244218: o[w][q] = relu(relu(relu((x[w]-y[q])@W1+b1)@W2+b2)@W3+b3)
// Algebraic rewrite: (x-y)@W1 = x@W1 - y@W1  -> precompute projections once.
// Kernel 1: Pp[s][row][h] partial projections (rows 0..511 = x, 512..1023 = y)
// Kernel 2: per 16x16 pair tile, reduce partials (+b1 on x side), then per-thread
//           h1[64] -> h2[32] -> o with W2/W3 as scalar (SGPR) operands.

#define IN_DIM 1600
#define H1D 64
#define H2D 32
#define NROW 512
#define KSPLIT 8
#define KCH (IN_DIM / KSPLIT)   // 200
#define RPW 8                   // rows per wave in proj kernel

__global__ __launch_bounds__(256) void proj_kernel(
    const float* __restrict__ x, const float* __restrict__ y,
    const float* __restrict__ W1, float* __restrict__ Pp) {
  const int lane = threadIdx.x & 63;
  // global wave id, forced wave-uniform so row reads scalarize to s_load
  const int gw = __builtin_amdgcn_readfirstlane((int)blockIdx.x * 4 + ((int)threadIdx.x >> 6));
  const int s = gw & (KSPLIT - 1);   // k-split 0..7
  const int g = gw >> 3;             // row-group 0..127
  const int row0 = g * RPW;          // 0..1016
  const float* __restrict__ base = (row0 < NROW) ? x : y;
  const int r0 = (row0 < NROW) ? row0 : (row0 - NROW);

  float acc[RPW];
#pragma unroll
  for (int r = 0; r < RPW; ++r) acc[r] = 0.f;

  const int i0 = s * KCH;
#pragma unroll 4
  for (int i = i0; i < i0 + KCH; ++i) {
    const float w = W1[i * H1D + lane];   // coalesced 256B per wave
#pragma unroll
    for (int r = 0; r < RPW; ++r)
      acc[r] = fmaf(base[(r0 + r) * IN_DIM + i], w, acc[r]);  // scalar operand
  }
#pragma unroll
  for (int r = 0; r < RPW; ++r)
    Pp[(s * 1024 + row0 + r) * H1D + lane] = acc[r];
}

__global__ __launch_bounds__(256) void pair_kernel(
    const float* __restrict__ Pp,
    const float* __restrict__ b1, const float* __restrict__ W2,
    const float* __restrict__ b2, const float* __restrict__ W3,
    const float* __restrict__ b3, float* __restrict__ out) {
  __shared__ float sX[16][68];   // pad 68: <=2-way LDS bank aliasing (free)
  __shared__ float sY[16][68];

  const int tid = threadIdx.x;
  const int wb = blockIdx.x * 16;   // x-row tile base
  const int qb = blockIdx.y * 16;   // y-row tile base

  // stage tiles: sum the 8 k-split partials; fold b1 into the X side
  for (int idx = tid; idx < 16 * H1D; idx += 256) {
    const int r = idx >> 6, h = idx & 63;
    float sx = 0.f, sy = 0.f;
#pragma unroll
    for (int s = 0; s < KSPLIT; ++s) {
      sx += Pp[(s * 1024 + wb + r) * H1D + h];
      sy += Pp[(s * 1024 + NROW + qb + r) * H1D + h];
    }
    sX[r][h] = sx + b1[h];
    sY[r][h] = sy;
  }
  __syncthreads();

  const int lq = tid & 15;    // y index within tile
  const int lw = tid >> 4;    // x index within tile

  float h1r[H1D];
#pragma unroll
  for (int h = 0; h < H1D; ++h) {
    const float v = sX[lw][h] - sY[lq][h];
    h1r[h] = v > 0.f ? v : 0.f;
  }

  float h2r[H2D];
#pragma unroll
  for (int k = 0; k < H2D; ++k) h2r[k] = b2[k];   // uniform -> s_load

#pragma unroll
  for (int h = 0; h < H1D; ++h) {
    const float a = h1r[h];
#pragma unroll
    for (int k = 0; k < H2D; ++k)
      h2r[k] = fmaf(a, W2[h * H2D + k], h2r[k]);  // uniform W2 -> SGPR operand
  }

  float o = b3[0];
#pragma unroll
  for (int k = 0; k < H2D; ++k) {
    const float v = h2r[k] > 0.f ? h2r[k] : 0.f;
    o = fmaf(v, W3[k], o);
  }
  out[(wb + lw) * NROW + (qb + lq)] = o > 0.f ? o : 0.f;
}

extern "C" void kernel_launch(void* const* d_in, const int* in_sizes, int n_in,
                              void* d_out, int out_size, void* d_ws, size_t ws_size,
                              hipStream_t stream) {
  const float* x  = (const float*)d_in[0];
  const float* y  = (const float*)d_in[1];
  const float* W1 = (const float*)d_in[2];
  const float* b1 = (const float*)d_in[3];
  const float* W2 = (const float*)d_in[4];
  const float* b2 = (const float*)d_in[5];
  const float* W3 = (const float*)d_in[6];
  const float* b3 = (const float*)d_in[7];
  float* out = (float*)d_out;
  float* Pp  = (float*)d_ws;   // needs KSPLIT*1024*64*4 = 2 MB

  // 1024 waves total: 128 row-groups x 8 k-splits, 4 waves/block
  proj_kernel<<<256, 256, 0, stream>>>(x, y, W1, Pp);
  // 32x32 blocks of 16x16 pairs
  pair_kernel<<<dim3(32, 32), 256, 0, stream>>>(Pp, b1, W2, b2, W3, b3, out);
}

// Round 2
// 31.389 us; speedup vs baseline: 1.1789x; 1.1789x over previous
//
#include <hip/hip_runtime.h>
#include <hip/hip_bf16.h>

// MLP_64450279244218: o[w][q] = relu(relu(relu((x[w]-y[q])@W1+b1)@W2+b2)@W3+b3)
// (x-y)@W1 = x@W1 - y@W1 -> precompute projections once.
// K1 proj:   Pp[32][1024][64] k-split partial projections (rows 0..511=x, 512..1023=y)
// K2 reduce: P[1024][64] = sum_s Pp (+b1 on x rows); also emits W2 in bf16 MFMA
//            B-fragment order (W2frag).
// K3 pair:   per 16x16 pair tile: h1 computed straight into bf16 A-fragments,
//            layer-2 via mfma_f32_16x16x32_bf16 (fp32 accum), layer-3 fp32 via
//            shfl_xor reduction over the C-fragment's 16 n-lanes.

#define IN_DIM 1600
#define H1D 64
#define H2D 32
#define NROW 512
#define KSPLIT 32
#define KCH (IN_DIM / KSPLIT)   // 50
#define RPW 8                   // rows per wave in proj

typedef short bf16x8 __attribute__((ext_vector_type(8)));
typedef float f32x4 __attribute__((ext_vector_type(4)));

static __device__ __forceinline__ short f2bf(float v) {
  __hip_bfloat16 h = __float2bfloat16(v);
  return *reinterpret_cast<short*>(&h);
}

// ---------------- K1: partial projections ----------------
__global__ __launch_bounds__(256) void proj_kernel(
    const float* __restrict__ x, const float* __restrict__ y,
    const float* __restrict__ W1, float* __restrict__ Pp) {
  const int lane = threadIdx.x & 63;
  const int gw = __builtin_amdgcn_readfirstlane((int)blockIdx.x * 4 + ((int)threadIdx.x >> 6));
  const int s = gw >> 7;          // k-split 0..31 (same for all 4 waves of a block -> W1 L1 reuse)
  const int g = gw & 127;         // row-group 0..127
  const int row0 = g * RPW;
  const float* __restrict__ base = (row0 < NROW) ? x : y;
  const int r0 = (row0 < NROW) ? row0 : (row0 - NROW);

  float acc[RPW];
#pragma unroll
  for (int r = 0; r < RPW; ++r) acc[r] = 0.f;

  const int i0 = s * KCH;
#pragma unroll 2
  for (int i = i0; i < i0 + KCH; ++i) {
    const float w = W1[i * H1D + lane];            // coalesced 256B/wave
#pragma unroll
    for (int r = 0; r < RPW; ++r)
      acc[r] = fmaf(base[(r0 + r) * IN_DIM + i], w, acc[r]);  // wave-uniform -> s_load
  }
#pragma unroll
  for (int r = 0; r < RPW; ++r)
    Pp[(s * 1024 + row0 + r) * H1D + lane] = acc[r];
}

// ---------------- K2: reduce partials + prep W2 fragments ----------------
__global__ __launch_bounds__(256) void reduce_kernel(
    const float* __restrict__ Pp, const float* __restrict__ b1,
    const float* __restrict__ W2,
    float* __restrict__ P, unsigned short* __restrict__ W2frag) {
  const int idx = blockIdx.x * 256 + threadIdx.x;   // 65536 = 1024*64
  const int row = idx >> 6, h = idx & 63;
  float sum = 0.f;
#pragma unroll
  for (int s = 0; s < KSPLIT; ++s) sum += Pp[(s * 1024 + row) * H1D + h];
  if (row < NROW) sum += b1[h];                     // fold b1 into x side
  P[row * H1D + h] = sum;

  if (blockIdx.x == 0) {
    // B-fragment layout for mfma_f32_16x16x32_bf16:
    // lane l holds B[k = ks*32 + (l>>4)*8 + j][n = nt*16 + (l&15)], j=0..7
    const int t = threadIdx.x;
    const int l = t & 63, ks = (t >> 6) & 1, nt = t >> 7;
#pragma unroll
    for (int j = 0; j < 8; ++j) {
      const int k = ks * 32 + (l >> 4) * 8 + j;
      const int n = nt * 16 + (l & 15);
      W2frag[((nt * 2 + ks) * 64 + l) * 8 + j] = (unsigned short)f2bf(W2[k * H2D + n]);
    }
  }
}

// ---------------- K3: pair tiles via MFMA ----------------
__global__ __launch_bounds__(256) void pair_kernel(
    const float* __restrict__ P, const unsigned short* __restrict__ W2frag,
    const float* __restrict__ b2, const float* __restrict__ W3,
    const float* __restrict__ b3, float* __restrict__ out) {
  __shared__ float sX[16][68];   // pad 68: <=2-way bank aliasing (free)
  __shared__ float sY[16][68];
  __shared__ float sO[16][16];

  const int tid = threadIdx.x;
  const int wave = tid >> 6, lane = tid & 63;
  const int l15 = lane & 15, l4 = lane >> 4;
  const int wb = blockIdx.x * 16;   // x tile base
  const int qb = blockIdx.y * 16;   // y tile base

  for (int idx = tid; idx < 16 * H1D; idx += 256) {
    const int r = idx >> 6, h = idx & 63;
    sX[r][h] = P[(wb + r) * H1D + h];            // b1 already folded
    sY[r][h] = P[(NROW + qb + r) * H1D + h];
  }
  __syncthreads();

  // B fragments (coalesced 16B/lane)
  bf16x8 bfr[2][2];
#pragma unroll
  for (int nt = 0; nt < 2; ++nt)
#pragma unroll
    for (int ks = 0; ks < 2; ++ks)
      bfr[nt][ks] = *reinterpret_cast<const bf16x8*>(&W2frag[((nt * 2 + ks) * 64 + lane) * 8]);

  // acc init = b2[n]  (C layout: col = lane&15 -> n = nt*16+l15)
  f32x4 acc[4][2];
  const float b2v0 = b2[l15], b2v1 = b2[16 + l15];
#pragma unroll
  for (int mt = 0; mt < 4; ++mt) {
#pragma unroll
    for (int r = 0; r < 4; ++r) { acc[mt][0][r] = b2v0; acc[mt][1][r] = b2v1; }
  }

  // A fragments: row = l15 (= lq), k = ks*32 + l4*8 + j ; value = relu(Px - Py)
#pragma unroll
  for (int ks = 0; ks < 2; ++ks) {
    const int kb = ks * 32 + l4 * 8;
    float yv[8];
#pragma unroll
    for (int j = 0; j < 8; ++j) yv[j] = sY[l15][kb + j];
#pragma unroll
    for (int mt = 0; mt < 4; ++mt) {
      const int lw = wave * 4 + mt;
      bf16x8 af;
#pragma unroll
      for (int j = 0; j < 8; ++j) {
        float v = sX[lw][kb + j] - yv[j];
        af[j] = f2bf(v > 0.f ? v : 0.f);
      }
#pragma unroll
      for (int nt = 0; nt < 2; ++nt)
        acc[mt][nt] = __builtin_amdgcn_mfma_f32_16x16x32_bf16(af, bfr[nt][ks], acc[mt][nt], 0, 0, 0);
    }
  }

  // layer 3: o = relu(sum_n relu(h2[n]) * W3[n] + b3)
  const float w3v0 = W3[l15], w3v1 = W3[16 + l15];
  const float b3v = b3[0];
#pragma unroll
  for (int mt = 0; mt < 4; ++mt) {
    float t[4];
#pragma unroll
    for (int r = 0; r < 4; ++r) {
      const float a0 = acc[mt][0][r] > 0.f ? acc[mt][0][r] : 0.f;
      const float a1 = acc[mt][1][r] > 0.f ? acc[mt][1][r] : 0.f;
      t[r] = fmaf(a0, w3v0, a1 * w3v1);
    }
#pragma unroll
    for (int off = 1; off < 16; off <<= 1) {
#pragma unroll
      for (int r = 0; r < 4; ++r) t[r] += __shfl_xor(t[r], off, 64);
    }
    if (l15 == 0) {
#pragma unroll
      for (int r = 0; r < 4; ++r) {
        const float o = t[r] + b3v;
        sO[wave * 4 + mt][l4 * 4 + r] = o > 0.f ? o : 0.f;   // [lw][lq]
      }
    }
  }
  __syncthreads();
  out[(wb + (tid >> 4)) * NROW + qb + (tid & 15)] = sO[tid >> 4][tid & 15];
}

extern "C" void kernel_launch(void* const* d_in, const int* in_sizes, int n_in,
                              void* d_out, int out_size, void* d_ws, size_t ws_size,
                              hipStream_t stream) {
  const float* x  = (const float*)d_in[0];
  const float* y  = (const float*)d_in[1];
  const float* W1 = (const float*)d_in[2];
  const float* b1 = (const float*)d_in[3];
  const float* W2 = (const float*)d_in[4];
  const float* b2 = (const float*)d_in[5];
  const float* W3 = (const float*)d_in[6];
  const float* b3 = (const float*)d_in[7];
  float* out = (float*)d_out;

  char* ws = (char*)d_ws;
  float* Pp = (float*)ws;                                   // 32*1024*64*4 = 8 MB
  float* P  = (float*)(ws + (size_t)KSPLIT * 1024 * H1D * 4);        // 256 KB
  unsigned short* W2frag = (unsigned short*)(ws + (size_t)KSPLIT * 1024 * H1D * 4 + 1024 * H1D * 4);

  proj_kernel<<<1024, 256, 0, stream>>>(x, y, W1, Pp);          // 4096 waves = 4/SIMD
  reduce_kernel<<<256, 256, 0, stream>>>(Pp, b1, W2, P, W2frag);
  pair_kernel<<<dim3(32, 32), 256, 0, stream>>>(P, W2frag, b2, W3, b3, out);
}

// Round 3
// 18.514 us; speedup vs baseline: 1.9987x; 1.6955x over previous
//
#include <hip/hip_runtime.h>
#include <hip/hip_bf16.h>

// MLP_64450279244218: o[w][q] = relu(relu(relu((x[w]-y[q])@W1+b1)@W2+b2)@W3+b3)
// (x-y)@W1 = x@W1 - y@W1 -> precompute projections once.
// K1 proj: P[1024][64] = [x;y]@W1 (+b1 on x rows), fp32. 256 blocks x 1024 thr;
//          block = 4 rows, 16 waves k-split 100 each, LDS reduce in-block
//          (no partials round-trip, no reduce kernel). Block 0 also emits W2
//          bf16 MFMA B-fragments.
// K2 pair: 16x16 pair tile: h1 built in bf16 A-fragments from P rows,
//          layer-2 = mfma_f32_16x16x32_bf16 (fp32 accum), layer-3 fp32 via
//          shfl_xor over the 16 n-lanes.

#define IN_DIM 1600
#define H1D 64
#define H2D 32
#define NROW 512

typedef short bf16x8 __attribute__((ext_vector_type(8)));
typedef float f32x4 __attribute__((ext_vector_type(4)));

static __device__ __forceinline__ short f2bf(float v) {
  __hip_bfloat16 h = __float2bfloat16(v);
  return *reinterpret_cast<short*>(&h);
}

// ---------------- K1: full projection, one kernel ----------------
__global__ __launch_bounds__(1024) void proj_kernel(
    const float* __restrict__ x, const float* __restrict__ y,
    const float* __restrict__ W1, const float* __restrict__ b1,
    const float* __restrict__ W2,
    float* __restrict__ P, unsigned short* __restrict__ W2frag) {
  __shared__ float pacc[16 * 4 * 64];   // 16 KB: [wave][row][h]
  const int tid = threadIdx.x;
  const int lane = tid & 63;
  const int w = __builtin_amdgcn_readfirstlane(tid >> 6);   // 0..15, wave-uniform
  const int row0 = (int)blockIdx.x * 4;
  const float* __restrict__ base = (row0 < NROW) ? x : y;
  const int r0 = (row0 < NROW) ? row0 : row0 - NROW;
  const int k0 = w * (IN_DIM / 16);    // 100 k per wave

  // per-row scalar pointers (SGPR) -> row reads become s_load_dwordx4
  const float* __restrict__ xr0 = base + (size_t)(r0 + 0) * IN_DIM + k0;
  const float* __restrict__ xr1 = base + (size_t)(r0 + 1) * IN_DIM + k0;
  const float* __restrict__ xr2 = base + (size_t)(r0 + 2) * IN_DIM + k0;
  const float* __restrict__ xr3 = base + (size_t)(r0 + 3) * IN_DIM + k0;
  const float* __restrict__ wp = W1 + (size_t)k0 * H1D + lane;

  float a0 = 0.f, a1 = 0.f, a2 = 0.f, a3 = 0.f;
#pragma unroll 4
  for (int i = 0; i < IN_DIM / 16; ++i) {
    const float wv = wp[i * H1D];          // coalesced 256B/wave
    a0 = fmaf(xr0[i], wv, a0);
    a1 = fmaf(xr1[i], wv, a1);
    a2 = fmaf(xr2[i], wv, a2);
    a3 = fmaf(xr3[i], wv, a3);
  }
  pacc[(w * 4 + 0) * 64 + lane] = a0;
  pacc[(w * 4 + 1) * 64 + lane] = a1;
  pacc[(w * 4 + 2) * 64 + lane] = a2;
  pacc[(w * 4 + 3) * 64 + lane] = a3;
  __syncthreads();

  if (tid < 256) {
    const int r = tid >> 6, h = tid & 63;
    float s = 0.f;
#pragma unroll
    for (int ww = 0; ww < 16; ++ww) s += pacc[(ww * 4 + r) * 64 + h];
    if (row0 < NROW) s += b1[h];           // fold b1 into x side only
    P[(size_t)(row0 + r) * H1D + h] = s;
  } else if (blockIdx.x == 0 && tid >= 512) {
    // W2 -> bf16 B-fragment order for mfma_f32_16x16x32_bf16:
    // lane l holds B[k = ks*32 + (l>>4)*8 + j][n = nt*16 + (l&15)], j=0..7
    const int t = tid - 512;
#pragma unroll
    for (int e = t; e < 4 * 64 * 8; e += 512) {
      const int f = e >> 9, l = (e >> 3) & 63, j = e & 7;
      const int ks = f & 1, nt = f >> 1;
      const int k = ks * 32 + (l >> 4) * 8 + j;
      const int n = nt * 16 + (l & 15);
      W2frag[e] = (unsigned short)f2bf(W2[k * H2D + n]);
    }
  }
}

// ---------------- K2: pair tiles via MFMA ----------------
__global__ __launch_bounds__(256) void pair_kernel(
    const float* __restrict__ P, const unsigned short* __restrict__ W2frag,
    const float* __restrict__ b2, const float* __restrict__ W3,
    const float* __restrict__ b3, float* __restrict__ out) {
  __shared__ float sX[16][68];   // 272B row stride = 17x16B -> b128 conflict-free
  __shared__ float sY[16][68];
  __shared__ float sO[16][16];

  const int tid = threadIdx.x;
  const int wave = tid >> 6, lane = tid & 63;
  const int l15 = lane & 15, l4 = lane >> 4;
  const int wb = blockIdx.x * 16, qb = blockIdx.y * 16;

  {  // stage both 16x64 tiles: one float4 per thread each
    const int r = tid >> 4, c = (tid & 15) * 4;
    const float4 vx = *reinterpret_cast<const float4*>(&P[(size_t)(wb + r) * H1D + c]);
    const float4 vy = *reinterpret_cast<const float4*>(&P[(size_t)(NROW + qb + r) * H1D + c]);
    *reinterpret_cast<float4*>(&sX[r][c]) = vx;
    *reinterpret_cast<float4*>(&sY[r][c]) = vy;
  }

  // B fragments (coalesced 16B/lane from ws)
  bf16x8 bfr[2][2];
#pragma unroll
  for (int nt = 0; nt < 2; ++nt)
#pragma unroll
    for (int ks = 0; ks < 2; ++ks)
      bfr[nt][ks] = *reinterpret_cast<const bf16x8*>(&W2frag[((nt * 2 + ks) * 64 + lane) * 8]);

  // acc init = b2[n]  (C col = l15)
  f32x4 acc[4][2];
  const float b2v0 = b2[l15], b2v1 = b2[16 + l15];
#pragma unroll
  for (int mt = 0; mt < 4; ++mt)
#pragma unroll
    for (int r = 0; r < 4; ++r) { acc[mt][0][r] = b2v0; acc[mt][1][r] = b2v1; }

  __syncthreads();

  // A fragments: A row = l15 (y index), k = ks*32 + l4*8 + j
#pragma unroll
  for (int ks = 0; ks < 2; ++ks) {
    const int kb = ks * 32 + l4 * 8;
    const float4 y0 = *reinterpret_cast<const float4*>(&sY[l15][kb]);
    const float4 y1 = *reinterpret_cast<const float4*>(&sY[l15][kb + 4]);
#pragma unroll
    for (int mt = 0; mt < 4; ++mt) {
      const int lw = wave * 4 + mt;
      const float4 x0 = *reinterpret_cast<const float4*>(&sX[lw][kb]);  // broadcast groups
      const float4 x1 = *reinterpret_cast<const float4*>(&sX[lw][kb + 4]);
      bf16x8 af;
      float v;
      v = x0.x - y0.x; af[0] = f2bf(v > 0.f ? v : 0.f);
      v = x0.y - y0.y; af[1] = f2bf(v > 0.f ? v : 0.f);
      v = x0.z - y0.z; af[2] = f2bf(v > 0.f ? v : 0.f);
      v = x0.w - y0.w; af[3] = f2bf(v > 0.f ? v : 0.f);
      v = x1.x - y1.x; af[4] = f2bf(v > 0.f ? v : 0.f);
      v = x1.y - y1.y; af[5] = f2bf(v > 0.f ? v : 0.f);
      v = x1.z - y1.z; af[6] = f2bf(v > 0.f ? v : 0.f);
      v = x1.w - y1.w; af[7] = f2bf(v > 0.f ? v : 0.f);
      acc[mt][0] = __builtin_amdgcn_mfma_f32_16x16x32_bf16(af, bfr[0][ks], acc[mt][0], 0, 0, 0);
      acc[mt][1] = __builtin_amdgcn_mfma_f32_16x16x32_bf16(af, bfr[1][ks], acc[mt][1], 0, 0, 0);
    }
  }

  // layer 3: o = relu(sum_n relu(h2[n]) * W3[n] + b3), reduce over 16 n-lanes
  const float w3v0 = W3[l15], w3v1 = W3[16 + l15];
  const float b3v = b3[0];
#pragma unroll
  for (int mt = 0; mt < 4; ++mt) {
    float t[4];
#pragma unroll
    for (int r = 0; r < 4; ++r) {
      const float q0 = acc[mt][0][r] > 0.f ? acc[mt][0][r] : 0.f;
      const float q1 = acc[mt][1][r] > 0.f ? acc[mt][1][r] : 0.f;
      t[r] = fmaf(q0, w3v0, q1 * w3v1);
    }
#pragma unroll
    for (int off = 1; off < 16; off <<= 1) {
#pragma unroll
      for (int r = 0; r < 4; ++r) t[r] += __shfl_xor(t[r], off, 64);
    }
    if (l15 == 0) {
#pragma unroll
      for (int r = 0; r < 4; ++r) {
        const float o = t[r] + b3v;
        sO[wave * 4 + mt][l4 * 4 + r] = o > 0.f ? o : 0.f;   // [lw][lq]
      }
    }
  }
  __syncthreads();
  out[(size_t)(wb + (tid >> 4)) * NROW + qb + (tid & 15)] = sO[tid >> 4][tid & 15];
}

extern "C" void kernel_launch(void* const* d_in, const int* in_sizes, int n_in,
                              void* d_out, int out_size, void* d_ws, size_t ws_size,
                              hipStream_t stream) {
  const float* x  = (const float*)d_in[0];
  const float* y  = (const float*)d_in[1];
  const float* W1 = (const float*)d_in[2];
  const float* b1 = (const float*)d_in[3];
  const float* W2 = (const float*)d_in[4];
  const float* b2 = (const float*)d_in[5];
  const float* W3 = (const float*)d_in[6];
  const float* b3 = (const float*)d_in[7];
  float* out = (float*)d_out;

  char* ws = (char*)d_ws;
  float* P = (float*)ws;                                   // 1024*64*4 = 256 KB
  unsigned short* W2frag = (unsigned short*)(ws + 1024 * H1D * 4);  // 4 KB

  proj_kernel<<<256, 1024, 0, stream>>>(x, y, W1, b1, W2, P, W2frag);
  pair_kernel<<<dim3(32, 32), 256, 0, stream>>>(P, W2frag, b2, W3, b3, out);
}